// Round 16
// baseline (103.389 us; speedup 1.0000x reference)
//
#include <hip/hip_runtime.h>
#include <hip/hip_bf16.h>

// LoRA MHSA fwd, fp16-MFMA. B=4,N=1024,D=768,H=12,hd=64,r=8
// Best-known config (round 11, ~100 us) with gemm1 retiled 64x96 -> 128x96
// (grid 8x32 = 256 blocks = exactly 1/CU; halves Ph panel re-reads).
//
// LoRA + bias folded into QKV GEMM K-dim (K=800); softmax scale 0.125*log2e
// folded into Q rows of Wext. pre = merged {W-fold+convert, proj convert, lora}.
// gemm_h<128,96,0>: QKV GEMM (3 blocks/CU exact), V written directly transposed.
// attn5: software-pipelined flash attn (best measured of 6 variants, ~42 us).
// gemm_h<128,96,1>: proj GEMM (1 block/CU exact).

typedef _Float16 half8 __attribute__((ext_vector_type(8)));
typedef float f32x4 __attribute__((ext_vector_type(4)));

typedef __attribute__((address_space(3))) unsigned int lds_u32;
typedef __attribute__((address_space(1))) const unsigned int glob_u32;

__device__ __forceinline__ void glds16(const void* g, void* l) {
    __builtin_amdgcn_global_load_lds((glob_u32*)g, (lds_u32*)l, 16, 0, 0);
}

__device__ __forceinline__ float pk2f16(float a, float b) {   // pack 2 f32 -> 2 f16 (RTZ), as f32 bits
    return __builtin_bit_cast(float, __builtin_amdgcn_cvt_pkrtz(a, b));
}

// 0.125 (softmax scale) * log2(e)
#define SMSCALE 0.18033688011112042f

// ---- ws layout (byte offsets) ----
constexpr size_t OFF_WX = 0;                                // 2304*800 f16
constexpr size_t OFF_PH = OFF_WX + (size_t)2304*800*2;      // 768*768 f16
constexpr size_t OFF_XE = OFF_PH + (size_t)768*768*2;       // 4096*800 f16
constexpr size_t OFF_QH = OFF_XE + (size_t)4096*800*2;
constexpr size_t OFF_KH = OFF_QH + (size_t)48*1024*64*2;
constexpr size_t OFF_VT = OFF_KH + (size_t)48*1024*64*2;    // [bh][64][1024] f16
constexpr size_t OFF_AO = OFF_VT + (size_t)48*1024*64*2;    // 4096*768 f16

// ---------------- pre: merged weight prep + lora ----------------
// blocks [0,2304): Wext row fold+convert (+LoRA-B cols, bias col)
// blocks [2304,2880): proj_w -> fp16
// blocks [2880,3392): lora rows, 8 per block: Xe = [fp16(x)|x@qA.T|x@kA.T|1|0*15]
__global__ __launch_bounds__(256)
void pre(const float* __restrict__ qkv_w, const float* __restrict__ qkv_b,
         const float* __restrict__ qw, const float* __restrict__ qbias,
         const float* __restrict__ kw, const float* __restrict__ kbias,
         const float* __restrict__ proj_w, const float* __restrict__ qB,
         const float* __restrict__ kB, const float* __restrict__ x,
         const float* __restrict__ qA, const float* __restrict__ kA,
         _Float16* __restrict__ Wx, _Float16* __restrict__ Ph,
         _Float16* __restrict__ Xe) {
    const int t = threadIdx.x, bb = blockIdx.x;
    if (bb < 2304) {
        const int n = bb;
        const float rs = (n < 768) ? SMSCALE : 1.0f;   // fold softmax scale into Q rows
        const float* wsrc = qkv_w + (size_t)n * 768;
        const float* fold = (n < 768) ? (qw + (size_t)n * 768)
                          : (n < 1536 ? (kw + (size_t)(n - 768) * 768) : nullptr);
        _Float16* dst = Wx + (size_t)n * 800;
#pragma unroll
        for (int i = 0; i < 3; ++i) {
            const int c = t + i * 256;
            float v = wsrc[c];
            if (fold) v += fold[c];
            dst[c] = (_Float16)(v * rs);
        }
        if (t < 32) {
            float v = 0.f;
            if (t < 8)       { if (n < 768) v = rs * 0.125f * qB[n * 8 + t]; }
            else if (t < 16) { if (n >= 768 && n < 1536) v = 0.125f * kB[(size_t)(n - 768) * 8 + (t - 8)]; }
            else if (t == 16) v = rs * (qkv_b[n] + (n < 768 ? qbias[n] : (n < 1536 ? kbias[n - 768] : 0.f)));
            dst[768 + t] = (_Float16)v;
        }
    } else if (bb < 2880) {
        const size_t idx = ((size_t)(bb - 2304) * 256 + t) * 4;
        const float4 v = *(const float4*)(proj_w + idx);
        _Float16* d = Ph + idx;
        d[0] = (_Float16)v.x; d[1] = (_Float16)v.y;
        d[2] = (_Float16)v.z; d[3] = (_Float16)v.w;
    } else {
        __shared__ float xs[8][768];
        const int m0 = (bb - 2880) * 8;
#pragma unroll
        for (int i = t * 4; i < 6144; i += 1024) {    // stage x rows + write fp16 copy
            const int r = i / 768, c = i - r * 768;
            const float4 v = *(const float4*)(x + (size_t)(m0 + r) * 768 + c);
            xs[r][c] = v.x; xs[r][c + 1] = v.y; xs[r][c + 2] = v.z; xs[r][c + 3] = v.w;
            _Float16* d = Xe + (size_t)(m0 + r) * 800 + c;
            d[0] = (_Float16)v.x; d[1] = (_Float16)v.y; d[2] = (_Float16)v.z; d[3] = (_Float16)v.w;
        }
        __syncthreads();

        const int j = t >> 4, lane = t & 15;          // j = output col 0..15
        const float* Arow = (j < 8) ? (qA + (size_t)j * 768) : (kA + (size_t)(j - 8) * 768);
        float accs[8] = {0.f, 0.f, 0.f, 0.f, 0.f, 0.f, 0.f, 0.f};
        for (int k = lane; k < 768; k += 16) {        // A loaded once; xs broadcast across j-groups
            const float a = Arow[k];
#pragma unroll
            for (int r = 0; r < 8; ++r) accs[r] += xs[r][k] * a;
        }
#pragma unroll
        for (int r = 0; r < 8; ++r) {
            float acc = accs[r];
            acc += __shfl_xor(acc, 1); acc += __shfl_xor(acc, 2);
            acc += __shfl_xor(acc, 4); acc += __shfl_xor(acc, 8);
            if (lane == 0) Xe[(size_t)(m0 + r) * 800 + 768 + j] = (_Float16)acc;
        }
        if (t < 128) {                                // tail cols 784..799
            const int r = t >> 4, c = t & 15;
            Xe[(size_t)(m0 + r) * 800 + 784 + c] = (c == 0) ? (_Float16)1.f : (_Float16)0.f;
        }
    }
}

// ---------------- 2-phase fp16 MFMA GEMM: C = A @ Bw.T ----------------
template<int BM, int BN, int MODE>
__global__ __launch_bounds__(256)
void gemm_h(const _Float16* __restrict__ A, const _Float16* __restrict__ Bw,
            const int lda, const int ldb, const int nsteps,
            const float* __restrict__ bias,
            _Float16* __restrict__ Oq, _Float16* __restrict__ Ok, _Float16* __restrict__ Ov,
            float* __restrict__ Co) {
    constexpr int CA = BM / 16, CB = BN / 16, CT = CA + CB;
    constexpr int MI = BM / 32, NI = BN / 32;
    __shared__ __align__(16) _Float16 As[2][BM * 32];
    __shared__ __align__(16) _Float16 Bs[2][BN * 32];
    const int t = threadIdx.x;
    const int w = t >> 6, l = t & 63;
    const int l15 = l & 15, lg = l >> 4;
    const int wm = w >> 1, wn = w & 1;

    const int gx = gridDim.x;
    int lin = blockIdx.y * gx + blockIdx.x;
    lin = (lin & 7) * ((gx * gridDim.y) >> 3) + (lin >> 3);   // XCD swizzle (nwg%8==0)
    const int n0 = (lin % gx) * BN, m0 = (lin / gx) * BM;

    const _Float16* Abase = A + (size_t)(m0 + l15) * lda + lg * 8;
    const _Float16* Bbase = Bw + (size_t)(n0 + l15) * ldb + lg * 8;

    f32x4 acc[MI][NI];
#pragma unroll
    for (int mi = 0; mi < MI; ++mi)
#pragma unroll
        for (int ni = 0; ni < NI; ++ni) acc[mi][ni] = 0.f;

#pragma unroll
    for (int c = w; c < CT; c += 4) {   // prologue: stage tile 0
        if (c < CA) glds16(Abase + (size_t)(c * 16) * lda, &As[0][c * 512]);
        else        glds16(Bbase + (size_t)((c - CA) * 16) * ldb, &Bs[0][(c - CA) * 512]);
    }
    __syncthreads();

    for (int s = 0; s < nsteps; ++s) {
        const int cur = s & 1;
        if (s + 1 < nsteps) {   // prefetch next tile before compute
            const int ko = (s + 1) * 32;
#pragma unroll
            for (int c = w; c < CT; c += 4) {
                if (c < CA) glds16(Abase + (size_t)(c * 16) * lda + ko, &As[cur ^ 1][c * 512]);
                else        glds16(Bbase + (size_t)((c - CA) * 16) * ldb + ko, &Bs[cur ^ 1][(c - CA) * 512]);
            }
        }
        half8 a[MI], b[NI];
#pragma unroll
        for (int mi = 0; mi < MI; ++mi) a[mi] = *(const half8*)&As[cur][(wm * MI + mi) * 512 + l * 8];
#pragma unroll
        for (int ni = 0; ni < NI; ++ni) b[ni] = *(const half8*)&Bs[cur][(wn * NI + ni) * 512 + l * 8];
#pragma unroll
        for (int mi = 0; mi < MI; ++mi)
#pragma unroll
            for (int ni = 0; ni < NI; ++ni)
                acc[mi][ni] = __builtin_amdgcn_mfma_f32_16x16x32_f16(a[mi], b[ni], acc[mi][ni], 0, 0, 0);
        __syncthreads();
    }

    if (MODE == 0) {
        const int sel = (n0 >= 1536) ? 2 : (n0 >= 768 ? 1 : 0);   // block-uniform (96 | 768)
        const int b_ = m0 >> 10, nnb = m0 & 1023;
        if (sel < 2) {
            _Float16* dst = (sel == 0) ? Oq : Ok;
            const int jb = n0 - sel * 768;
#pragma unroll
            for (int mi = 0; mi < MI; ++mi)
#pragma unroll
                for (int reg = 0; reg < 4; ++reg) {
                    const int nn = nnb + wm * (BM / 2) + mi * 16 + lg * 4 + reg;
#pragma unroll
                    for (int ni = 0; ni < NI; ++ni) {
                        const int jj = jb + wn * (BN / 2) + ni * 16 + l15;
                        const int h = jj >> 6, d = jj & 63;
                        dst[(((size_t)(b_ * 12 + h)) * 1024 + nn) * 64 + d] = (_Float16)acc[mi][ni][reg];
                    }
                }
        } else {   // V: write transposed, 4 tokens packed per 8B store
#pragma unroll
            for (int mi = 0; mi < MI; ++mi) {
                const int nn = nnb + wm * (BM / 2) + mi * 16 + lg * 4;
#pragma unroll
                for (int ni = 0; ni < NI; ++ni) {
                    const int jj = (n0 - 1536) + wn * (BN / 2) + ni * 16 + l15;
                    const int h = jj >> 6, d = jj & 63;
                    float2 pv;
                    pv.x = pk2f16(acc[mi][ni][0], acc[mi][ni][1]);
                    pv.y = pk2f16(acc[mi][ni][2], acc[mi][ni][3]);
                    *(float2*)&Ov[(((size_t)(b_ * 12 + h)) * 64 + d) * 1024 + nn] = pv;
                }
            }
        }
    } else {
#pragma unroll
        for (int mi = 0; mi < MI; ++mi)
#pragma unroll
            for (int reg = 0; reg < 4; ++reg) {
                const int m = m0 + wm * (BM / 2) + mi * 16 + lg * 4 + reg;
#pragma unroll
                for (int ni = 0; ni < NI; ++ni) {
                    const int n = n0 + wn * (BN / 2) + ni * 16 + l15;
                    Co[(size_t)m * 768 + n] = acc[mi][ni][reg] + bias[n];
                }
            }
    }
}

// ---------------- attn5: software-pipelined flash attn ----------------
// 768 blocks (16 qb x 48 bh) x 2 waves; wave = 32 q-rows, 64-key tiles, 16 tiles.
// Per iter kb: stage K(kb+2), V(kb+1) (async) || QK(kb+1) || PV(kb) || exp(kb+1);
// one barrier per iter. K staged 2-ahead, V 1-ahead.
#define STAGEK(kbt, buf) { \
_Pragma("unroll") \
    for (int i = 0; i < 4; ++i) { \
        const int c = w * 4 + i; \
        glds16(Kp + (size_t)((kbt) * 64 + (c >> 1) * 16 + l15) * 64 + (c & 1) * 32 + lg * 8, &Ks[buf][c * 512]); \
    } }
#define STAGEV(kbt, buf) { \
_Pragma("unroll") \
    for (int i = 0; i < 4; ++i) { \
        const int c = w * 4 + i; \
        glds16(Vp + (size_t)((c >> 1) * 16 + l15) * 1024 + (kbt) * 64 + (c & 1) * 32 + lg * 8, &Vs[buf][c * 512]); \
    } }
#define QK(buf, s) { \
    half8 kreg[8]; \
_Pragma("unroll") \
    for (int c = 0; c < 8; ++c) kreg[c] = *(const half8*)&Ks[buf][c * 512 + l * 8]; \
_Pragma("unroll") \
    for (int mi = 0; mi < 2; ++mi) \
_Pragma("unroll") \
        for (int nj = 0; nj < 4; ++nj) { \
            s[mi][nj] = 0.f; \
_Pragma("unroll") \
            for (int kh = 0; kh < 2; ++kh) \
                s[mi][nj] = __builtin_amdgcn_mfma_f32_16x16x32_f16(kreg[nj * 2 + kh], qf[mi][kh], s[mi][nj], 0, 0, 0); \
        } }
#define EXPP(ph, s) { \
_Pragma("unroll") \
    for (int mi = 0; mi < 2; ++mi) { \
        float ls = 0.f; \
_Pragma("unroll") \
        for (int nj = 0; nj < 4; ++nj) { \
            const float p0 = __builtin_amdgcn_exp2f(s[mi][nj][0]); \
            const float p1 = __builtin_amdgcn_exp2f(s[mi][nj][1]); \
            const float p2 = __builtin_amdgcn_exp2f(s[mi][nj][2]); \
            const float p3 = __builtin_amdgcn_exp2f(s[mi][nj][3]); \
            ls += (p0 + p1) + (p2 + p3); \
            float2 pk; \
            pk.x = pk2f16(p0, p1); \
            pk.y = pk2f16(p2, p3); \
            const int off = (mi * 2 + (nj >> 1)) * 512 + (2 * (nj & 1) + (lg >> 1)) * 128 \
                          + l15 * 8 + 4 * (lg & 1); \
            *(float2*)&Ps[w][ph][off] = pk; \
        } \
        lsum[mi] += ls; \
    } }
#define PV(ph, buf) { \
    half8 pf[2][2]; \
_Pragma("unroll") \
    for (int mi = 0; mi < 2; ++mi) \
_Pragma("unroll") \
        for (int kh = 0; kh < 2; ++kh) \
            pf[mi][kh] = *(const half8*)&Ps[w][ph][(mi * 2 + kh) * 512 + l * 8]; \
_Pragma("unroll") \
    for (int fj = 0; fj < 4; ++fj) \
_Pragma("unroll") \
        for (int kh = 0; kh < 2; ++kh) { \
            const half8 vf = *(const half8*)&Vs[buf][(fj * 2 + kh) * 512 + l * 8]; \
_Pragma("unroll") \
            for (int mi = 0; mi < 2; ++mi) \
                o[mi][fj] = __builtin_amdgcn_mfma_f32_16x16x32_f16(pf[mi][kh], vf, o[mi][fj], 0, 0, 0); \
        } }

__global__ __launch_bounds__(128)
void attn5(const _Float16* __restrict__ Q, const _Float16* __restrict__ K,
           const _Float16* __restrict__ Vt, _Float16* __restrict__ AO) {
    __shared__ __align__(16) _Float16 Ks[2][4096];
    __shared__ __align__(16) _Float16 Vs[2][4096];
    __shared__ __align__(16) _Float16 Ps[2][2][2048];   // [wave][phase]
    __shared__ float sums[2][32];
    const int t = threadIdx.x;
    const int w = t >> 6, l = t & 63;
    const int l15 = l & 15, lg = l >> 4;

    int lin = blockIdx.y * 16 + blockIdx.x;          // 768 blocks
    lin = (lin & 7) * 96 + (lin >> 3);               // XCD swizzle
    const int qb = lin & 15, bh = lin >> 4;

    const _Float16* Qp = Q  + (size_t)bh * 65536;
    const _Float16* Kp = K  + (size_t)bh * 65536;
    const _Float16* Vp = Vt + (size_t)bh * 65536;    // [64][1024]

    STAGEK(0, 0); STAGEK(1, 1); STAGEV(0, 0);
    half8 qf[2][2];
#pragma unroll
    for (int mi = 0; mi < 2; ++mi)
#pragma unroll
        for (int kh = 0; kh < 2; ++kh)
            qf[mi][kh] = *(const half8*)&Qp[(size_t)(qb * 64 + w * 32 + mi * 16 + l15) * 64 + kh * 32 + lg * 8];

    f32x4 o[2][4];
#pragma unroll
    for (int mi = 0; mi < 2; ++mi)
#pragma unroll
        for (int fj = 0; fj < 4; ++fj) o[mi][fj] = 0.f;
    float lsum[2] = {0.f, 0.f};
    __syncthreads();

    {   // QK(0) + exp -> Ps[*][0]
        f32x4 s[2][4];
        QK(0, s);
        EXPP(0, s);
    }
    __syncthreads();

    for (int kb = 0; kb < 15; ++kb) {
        const int cb = kb & 1, nb = cb ^ 1;
        if (kb + 2 < 16) STAGEK(kb + 2, cb);
        STAGEV(kb + 1, nb);
        f32x4 s[2][4];
        __builtin_amdgcn_s_setprio(1);
        QK(nb, s);
        PV(cb, cb);
        __builtin_amdgcn_s_setprio(0);
        EXPP(nb, s);
        __syncthreads();
    }
    PV(1, 1);

#pragma unroll
    for (int mi = 0; mi < 2; ++mi) {
        float tot = lsum[mi];
        tot += __shfl_xor(tot, 16);
        tot += __shfl_xor(tot, 32);
        if (lg == 0) sums[w][mi * 16 + l15] = tot;
    }
    __builtin_amdgcn_wave_barrier();

    const int b_ = bh / 12, h = bh % 12;
#pragma unroll
    for (int mi = 0; mi < 2; ++mi)
#pragma unroll
        for (int reg = 0; reg < 4; ++reg) {
            const float inv = 1.f / sums[w][mi * 16 + lg * 4 + reg];
            const int tok = qb * 64 + w * 32 + mi * 16 + lg * 4 + reg;
            const size_t base = ((size_t)(b_ * 1024 + tok)) * 768 + h * 64;
#pragma unroll
            for (int fj = 0; fj < 4; ++fj)
                AO[base + fj * 16 + l15] = (_Float16)(o[mi][fj][reg] * inv);
        }
}

// ---------------- launcher ----------------
extern "C" void kernel_launch(void* const* d_in, const int* in_sizes, int n_in,
                              void* d_out, int out_size, void* d_ws, size_t ws_size,
                              hipStream_t stream) {
    (void)in_sizes; (void)n_in; (void)out_size; (void)ws_size;
    const float* x      = (const float*)d_in[0];
    const float* qkv_w  = (const float*)d_in[1];
    const float* qkv_b  = (const float*)d_in[2];
    const float* q_bw   = (const float*)d_in[3];
    const float* q_bb   = (const float*)d_in[4];
    const float* q_A    = (const float*)d_in[5];
    const float* q_B    = (const float*)d_in[6];
    const float* k_bw   = (const float*)d_in[7];
    const float* k_bb   = (const float*)d_in[8];
    const float* k_A    = (const float*)d_in[9];
    const float* k_B    = (const float*)d_in[10];
    const float* proj_w = (const float*)d_in[11];
    const float* proj_b = (const float*)d_in[12];
    float* out = (float*)d_out;
    char*  ws  = (char*)d_ws;

    _Float16* Wx = (_Float16*)(ws + OFF_WX);
    _Float16* Ph = (_Float16*)(ws + OFF_PH);
    _Float16* Xe = (_Float16*)(ws + OFF_XE);
    _Float16* Qh = (_Float16*)(ws + OFF_QH);
    _Float16* Kh = (_Float16*)(ws + OFF_KH);
    _Float16* Vt = (_Float16*)(ws + OFF_VT);
    _Float16* AO = (_Float16*)(ws + OFF_AO);

    pre<<<dim3(3392), dim3(256), 0, stream>>>(qkv_w, qkv_b, q_bw, q_bb, k_bw, k_bb,
                                              proj_w, q_B, k_B, x, q_A, k_A, Wx, Ph, Xe);
    gemm_h<128, 96, 0><<<dim3(24, 32), dim3(256), 0, stream>>>(
        Xe, Wx, 800, 800, 25, nullptr, Qh, Kh, Vt, nullptr);
    attn5<<<dim3(16, 48), dim3(128), 0, stream>>>(Qh, Kh, Vt, AO);
    gemm_h<128, 96, 1><<<dim3(8, 32), dim3(256), 0, stream>>>(
        AO, Ph, 768, 768, 24, proj_b, nullptr, nullptr, nullptr, out);
}

// Round 17
// 99.456 us; speedup vs baseline: 1.0396x; 1.0396x over previous
//
#include <hip/hip_runtime.h>
#include <hip/hip_bf16.h>

// LoRA MHSA fwd, fp16-MFMA. B=4,N=1024,D=768,H=12,hd=64,r=8
// FINAL best config (= round 11/15, 99.7/100.1 us): r16's gemm1 128x96 retile
// was -3% (1 block/CU can't hide prologue/drain); reverted to 64x96.
//
// LoRA + bias folded into QKV GEMM K-dim (K=800); softmax scale 0.125*log2e
// folded into Q rows of Wext. pre = merged {W-fold+convert, proj convert, lora}.
// gemm_h<128,96,0>: QKV GEMM (3 blocks/CU exact), V written directly transposed.
// attn5: software-pipelined flash attn (best measured of 6 variants, ~42 us).
// gemm_h<64,96,1>: proj GEMM (2 blocks/CU exact).

typedef _Float16 half8 __attribute__((ext_vector_type(8)));
typedef float f32x4 __attribute__((ext_vector_type(4)));

typedef __attribute__((address_space(3))) unsigned int lds_u32;
typedef __attribute__((address_space(1))) const unsigned int glob_u32;

__device__ __forceinline__ void glds16(const void* g, void* l) {
    __builtin_amdgcn_global_load_lds((glob_u32*)g, (lds_u32*)l, 16, 0, 0);
}

__device__ __forceinline__ float pk2f16(float a, float b) {   // pack 2 f32 -> 2 f16 (RTZ), as f32 bits
    return __builtin_bit_cast(float, __builtin_amdgcn_cvt_pkrtz(a, b));
}

// 0.125 (softmax scale) * log2(e)
#define SMSCALE 0.18033688011112042f

// ---- ws layout (byte offsets) ----
constexpr size_t OFF_WX = 0;                                // 2304*800 f16
constexpr size_t OFF_PH = OFF_WX + (size_t)2304*800*2;      // 768*768 f16
constexpr size_t OFF_XE = OFF_PH + (size_t)768*768*2;       // 4096*800 f16
constexpr size_t OFF_QH = OFF_XE + (size_t)4096*800*2;
constexpr size_t OFF_KH = OFF_QH + (size_t)48*1024*64*2;
constexpr size_t OFF_VT = OFF_KH + (size_t)48*1024*64*2;    // [bh][64][1024] f16
constexpr size_t OFF_AO = OFF_VT + (size_t)48*1024*64*2;    // 4096*768 f16

// ---------------- pre: merged weight prep + lora ----------------
// blocks [0,2304): Wext row fold+convert (+LoRA-B cols, bias col)
// blocks [2304,2880): proj_w -> fp16
// blocks [2880,3392): lora rows, 8 per block: Xe = [fp16(x)|x@qA.T|x@kA.T|1|0*15]
__global__ __launch_bounds__(256)
void pre(const float* __restrict__ qkv_w, const float* __restrict__ qkv_b,
         const float* __restrict__ qw, const float* __restrict__ qbias,
         const float* __restrict__ kw, const float* __restrict__ kbias,
         const float* __restrict__ proj_w, const float* __restrict__ qB,
         const float* __restrict__ kB, const float* __restrict__ x,
         const float* __restrict__ qA, const float* __restrict__ kA,
         _Float16* __restrict__ Wx, _Float16* __restrict__ Ph,
         _Float16* __restrict__ Xe) {
    const int t = threadIdx.x, bb = blockIdx.x;
    if (bb < 2304) {
        const int n = bb;
        const float rs = (n < 768) ? SMSCALE : 1.0f;   // fold softmax scale into Q rows
        const float* wsrc = qkv_w + (size_t)n * 768;
        const float* fold = (n < 768) ? (qw + (size_t)n * 768)
                          : (n < 1536 ? (kw + (size_t)(n - 768) * 768) : nullptr);
        _Float16* dst = Wx + (size_t)n * 800;
#pragma unroll
        for (int i = 0; i < 3; ++i) {
            const int c = t + i * 256;
            float v = wsrc[c];
            if (fold) v += fold[c];
            dst[c] = (_Float16)(v * rs);
        }
        if (t < 32) {
            float v = 0.f;
            if (t < 8)       { if (n < 768) v = rs * 0.125f * qB[n * 8 + t]; }
            else if (t < 16) { if (n >= 768 && n < 1536) v = 0.125f * kB[(size_t)(n - 768) * 8 + (t - 8)]; }
            else if (t == 16) v = rs * (qkv_b[n] + (n < 768 ? qbias[n] : (n < 1536 ? kbias[n - 768] : 0.f)));
            dst[768 + t] = (_Float16)v;
        }
    } else if (bb < 2880) {
        const size_t idx = ((size_t)(bb - 2304) * 256 + t) * 4;
        const float4 v = *(const float4*)(proj_w + idx);
        _Float16* d = Ph + idx;
        d[0] = (_Float16)v.x; d[1] = (_Float16)v.y;
        d[2] = (_Float16)v.z; d[3] = (_Float16)v.w;
    } else {
        __shared__ float xs[8][768];
        const int m0 = (bb - 2880) * 8;
#pragma unroll
        for (int i = t * 4; i < 6144; i += 1024) {    // stage x rows + write fp16 copy
            const int r = i / 768, c = i - r * 768;
            const float4 v = *(const float4*)(x + (size_t)(m0 + r) * 768 + c);
            xs[r][c] = v.x; xs[r][c + 1] = v.y; xs[r][c + 2] = v.z; xs[r][c + 3] = v.w;
            _Float16* d = Xe + (size_t)(m0 + r) * 800 + c;
            d[0] = (_Float16)v.x; d[1] = (_Float16)v.y; d[2] = (_Float16)v.z; d[3] = (_Float16)v.w;
        }
        __syncthreads();

        const int j = t >> 4, lane = t & 15;          // j = output col 0..15
        const float* Arow = (j < 8) ? (qA + (size_t)j * 768) : (kA + (size_t)(j - 8) * 768);
        float accs[8] = {0.f, 0.f, 0.f, 0.f, 0.f, 0.f, 0.f, 0.f};
        for (int k = lane; k < 768; k += 16) {        // A loaded once; xs broadcast across j-groups
            const float a = Arow[k];
#pragma unroll
            for (int r = 0; r < 8; ++r) accs[r] += xs[r][k] * a;
        }
#pragma unroll
        for (int r = 0; r < 8; ++r) {
            float acc = accs[r];
            acc += __shfl_xor(acc, 1); acc += __shfl_xor(acc, 2);
            acc += __shfl_xor(acc, 4); acc += __shfl_xor(acc, 8);
            if (lane == 0) Xe[(size_t)(m0 + r) * 800 + 768 + j] = (_Float16)acc;
        }
        if (t < 128) {                                // tail cols 784..799
            const int r = t >> 4, c = t & 15;
            Xe[(size_t)(m0 + r) * 800 + 784 + c] = (c == 0) ? (_Float16)1.f : (_Float16)0.f;
        }
    }
}

// ---------------- 2-phase fp16 MFMA GEMM: C = A @ Bw.T ----------------
template<int BM, int BN, int MODE>
__global__ __launch_bounds__(256)
void gemm_h(const _Float16* __restrict__ A, const _Float16* __restrict__ Bw,
            const int lda, const int ldb, const int nsteps,
            const float* __restrict__ bias,
            _Float16* __restrict__ Oq, _Float16* __restrict__ Ok, _Float16* __restrict__ Ov,
            float* __restrict__ Co) {
    constexpr int CA = BM / 16, CB = BN / 16, CT = CA + CB;
    constexpr int MI = BM / 32, NI = BN / 32;
    __shared__ __align__(16) _Float16 As[2][BM * 32];
    __shared__ __align__(16) _Float16 Bs[2][BN * 32];
    const int t = threadIdx.x;
    const int w = t >> 6, l = t & 63;
    const int l15 = l & 15, lg = l >> 4;
    const int wm = w >> 1, wn = w & 1;

    const int gx = gridDim.x;
    int lin = blockIdx.y * gx + blockIdx.x;
    lin = (lin & 7) * ((gx * gridDim.y) >> 3) + (lin >> 3);   // XCD swizzle (nwg%8==0)
    const int n0 = (lin % gx) * BN, m0 = (lin / gx) * BM;

    const _Float16* Abase = A + (size_t)(m0 + l15) * lda + lg * 8;
    const _Float16* Bbase = Bw + (size_t)(n0 + l15) * ldb + lg * 8;

    f32x4 acc[MI][NI];
#pragma unroll
    for (int mi = 0; mi < MI; ++mi)
#pragma unroll
        for (int ni = 0; ni < NI; ++ni) acc[mi][ni] = 0.f;

#pragma unroll
    for (int c = w; c < CT; c += 4) {   // prologue: stage tile 0
        if (c < CA) glds16(Abase + (size_t)(c * 16) * lda, &As[0][c * 512]);
        else        glds16(Bbase + (size_t)((c - CA) * 16) * ldb, &Bs[0][(c - CA) * 512]);
    }
    __syncthreads();

    for (int s = 0; s < nsteps; ++s) {
        const int cur = s & 1;
        if (s + 1 < nsteps) {   // prefetch next tile before compute
            const int ko = (s + 1) * 32;
#pragma unroll
            for (int c = w; c < CT; c += 4) {
                if (c < CA) glds16(Abase + (size_t)(c * 16) * lda + ko, &As[cur ^ 1][c * 512]);
                else        glds16(Bbase + (size_t)((c - CA) * 16) * ldb + ko, &Bs[cur ^ 1][(c - CA) * 512]);
            }
        }
        half8 a[MI], b[NI];
#pragma unroll
        for (int mi = 0; mi < MI; ++mi) a[mi] = *(const half8*)&As[cur][(wm * MI + mi) * 512 + l * 8];
#pragma unroll
        for (int ni = 0; ni < NI; ++ni) b[ni] = *(const half8*)&Bs[cur][(wn * NI + ni) * 512 + l * 8];
#pragma unroll
        for (int mi = 0; mi < MI; ++mi)
#pragma unroll
            for (int ni = 0; ni < NI; ++ni)
                acc[mi][ni] = __builtin_amdgcn_mfma_f32_16x16x32_f16(a[mi], b[ni], acc[mi][ni], 0, 0, 0);
        __syncthreads();
    }

    if (MODE == 0) {
        const int sel = (n0 >= 1536) ? 2 : (n0 >= 768 ? 1 : 0);   // block-uniform (96 | 768)
        const int b_ = m0 >> 10, nnb = m0 & 1023;
        if (sel < 2) {
            _Float16* dst = (sel == 0) ? Oq : Ok;
            const int jb = n0 - sel * 768;
#pragma unroll
            for (int mi = 0; mi < MI; ++mi)
#pragma unroll
                for (int reg = 0; reg < 4; ++reg) {
                    const int nn = nnb + wm * (BM / 2) + mi * 16 + lg * 4 + reg;
#pragma unroll
                    for (int ni = 0; ni < NI; ++ni) {
                        const int jj = jb + wn * (BN / 2) + ni * 16 + l15;
                        const int h = jj >> 6, d = jj & 63;
                        dst[(((size_t)(b_ * 12 + h)) * 1024 + nn) * 64 + d] = (_Float16)acc[mi][ni][reg];
                    }
                }
        } else {   // V: write transposed, 4 tokens packed per 8B store
#pragma unroll
            for (int mi = 0; mi < MI; ++mi) {
                const int nn = nnb + wm * (BM / 2) + mi * 16 + lg * 4;
#pragma unroll
                for (int ni = 0; ni < NI; ++ni) {
                    const int jj = (n0 - 1536) + wn * (BN / 2) + ni * 16 + l15;
                    const int h = jj >> 6, d = jj & 63;
                    float2 pv;
                    pv.x = pk2f16(acc[mi][ni][0], acc[mi][ni][1]);
                    pv.y = pk2f16(acc[mi][ni][2], acc[mi][ni][3]);
                    *(float2*)&Ov[(((size_t)(b_ * 12 + h)) * 64 + d) * 1024 + nn] = pv;
                }
            }
        }
    } else {
#pragma unroll
        for (int mi = 0; mi < MI; ++mi)
#pragma unroll
            for (int reg = 0; reg < 4; ++reg) {
                const int m = m0 + wm * (BM / 2) + mi * 16 + lg * 4 + reg;
#pragma unroll
                for (int ni = 0; ni < NI; ++ni) {
                    const int n = n0 + wn * (BN / 2) + ni * 16 + l15;
                    Co[(size_t)m * 768 + n] = acc[mi][ni][reg] + bias[n];
                }
            }
    }
}

// ---------------- attn5: software-pipelined flash attn ----------------
// 768 blocks (16 qb x 48 bh) x 2 waves; wave = 32 q-rows, 64-key tiles, 16 tiles.
// Per iter kb: stage K(kb+2), V(kb+1) (async) || QK(kb+1) || PV(kb) || exp(kb+1);
// one barrier per iter. K staged 2-ahead, V 1-ahead.
#define STAGEK(kbt, buf) { \
_Pragma("unroll") \
    for (int i = 0; i < 4; ++i) { \
        const int c = w * 4 + i; \
        glds16(Kp + (size_t)((kbt) * 64 + (c >> 1) * 16 + l15) * 64 + (c & 1) * 32 + lg * 8, &Ks[buf][c * 512]); \
    } }
#define STAGEV(kbt, buf) { \
_Pragma("unroll") \
    for (int i = 0; i < 4; ++i) { \
        const int c = w * 4 + i; \
        glds16(Vp + (size_t)((c >> 1) * 16 + l15) * 1024 + (kbt) * 64 + (c & 1) * 32 + lg * 8, &Vs[buf][c * 512]); \
    } }
#define QK(buf, s) { \
    half8 kreg[8]; \
_Pragma("unroll") \
    for (int c = 0; c < 8; ++c) kreg[c] = *(const half8*)&Ks[buf][c * 512 + l * 8]; \
_Pragma("unroll") \
    for (int mi = 0; mi < 2; ++mi) \
_Pragma("unroll") \
        for (int nj = 0; nj < 4; ++nj) { \
            s[mi][nj] = 0.f; \
_Pragma("unroll") \
            for (int kh = 0; kh < 2; ++kh) \
                s[mi][nj] = __builtin_amdgcn_mfma_f32_16x16x32_f16(kreg[nj * 2 + kh], qf[mi][kh], s[mi][nj], 0, 0, 0); \
        } }
#define EXPP(ph, s) { \
_Pragma("unroll") \
    for (int mi = 0; mi < 2; ++mi) { \
        float ls = 0.f; \
_Pragma("unroll") \
        for (int nj = 0; nj < 4; ++nj) { \
            const float p0 = __builtin_amdgcn_exp2f(s[mi][nj][0]); \
            const float p1 = __builtin_amdgcn_exp2f(s[mi][nj][1]); \
            const float p2 = __builtin_amdgcn_exp2f(s[mi][nj][2]); \
            const float p3 = __builtin_amdgcn_exp2f(s[mi][nj][3]); \
            ls += (p0 + p1) + (p2 + p3); \
            float2 pk; \
            pk.x = pk2f16(p0, p1); \
            pk.y = pk2f16(p2, p3); \
            const int off = (mi * 2 + (nj >> 1)) * 512 + (2 * (nj & 1) + (lg >> 1)) * 128 \
                          + l15 * 8 + 4 * (lg & 1); \
            *(float2*)&Ps[w][ph][off] = pk; \
        } \
        lsum[mi] += ls; \
    } }
#define PV(ph, buf) { \
    half8 pf[2][2]; \
_Pragma("unroll") \
    for (int mi = 0; mi < 2; ++mi) \
_Pragma("unroll") \
        for (int kh = 0; kh < 2; ++kh) \
            pf[mi][kh] = *(const half8*)&Ps[w][ph][(mi * 2 + kh) * 512 + l * 8]; \
_Pragma("unroll") \
    for (int fj = 0; fj < 4; ++fj) \
_Pragma("unroll") \
        for (int kh = 0; kh < 2; ++kh) { \
            const half8 vf = *(const half8*)&Vs[buf][(fj * 2 + kh) * 512 + l * 8]; \
_Pragma("unroll") \
            for (int mi = 0; mi < 2; ++mi) \
                o[mi][fj] = __builtin_amdgcn_mfma_f32_16x16x32_f16(pf[mi][kh], vf, o[mi][fj], 0, 0, 0); \
        } }

__global__ __launch_bounds__(128)
void attn5(const _Float16* __restrict__ Q, const _Float16* __restrict__ K,
           const _Float16* __restrict__ Vt, _Float16* __restrict__ AO) {
    __shared__ __align__(16) _Float16 Ks[2][4096];
    __shared__ __align__(16) _Float16 Vs[2][4096];
    __shared__ __align__(16) _Float16 Ps[2][2][2048];   // [wave][phase]
    __shared__ float sums[2][32];
    const int t = threadIdx.x;
    const int w = t >> 6, l = t & 63;
    const int l15 = l & 15, lg = l >> 4;

    int lin = blockIdx.y * 16 + blockIdx.x;          // 768 blocks
    lin = (lin & 7) * 96 + (lin >> 3);               // XCD swizzle
    const int qb = lin & 15, bh = lin >> 4;

    const _Float16* Qp = Q  + (size_t)bh * 65536;
    const _Float16* Kp = K  + (size_t)bh * 65536;
    const _Float16* Vp = Vt + (size_t)bh * 65536;    // [64][1024]

    STAGEK(0, 0); STAGEK(1, 1); STAGEV(0, 0);
    half8 qf[2][2];
#pragma unroll
    for (int mi = 0; mi < 2; ++mi)
#pragma unroll
        for (int kh = 0; kh < 2; ++kh)
            qf[mi][kh] = *(const half8*)&Qp[(size_t)(qb * 64 + w * 32 + mi * 16 + l15) * 64 + kh * 32 + lg * 8];

    f32x4 o[2][4];
#pragma unroll
    for (int mi = 0; mi < 2; ++mi)
#pragma unroll
        for (int fj = 0; fj < 4; ++fj) o[mi][fj] = 0.f;
    float lsum[2] = {0.f, 0.f};
    __syncthreads();

    {   // QK(0) + exp -> Ps[*][0]
        f32x4 s[2][4];
        QK(0, s);
        EXPP(0, s);
    }
    __syncthreads();

    for (int kb = 0; kb < 15; ++kb) {
        const int cb = kb & 1, nb = cb ^ 1;
        if (kb + 2 < 16) STAGEK(kb + 2, cb);
        STAGEV(kb + 1, nb);
        f32x4 s[2][4];
        __builtin_amdgcn_s_setprio(1);
        QK(nb, s);
        PV(cb, cb);
        __builtin_amdgcn_s_setprio(0);
        EXPP(nb, s);
        __syncthreads();
    }
    PV(1, 1);

#pragma unroll
    for (int mi = 0; mi < 2; ++mi) {
        float tot = lsum[mi];
        tot += __shfl_xor(tot, 16);
        tot += __shfl_xor(tot, 32);
        if (lg == 0) sums[w][mi * 16 + l15] = tot;
    }
    __builtin_amdgcn_wave_barrier();

    const int b_ = bh / 12, h = bh % 12;
#pragma unroll
    for (int mi = 0; mi < 2; ++mi)
#pragma unroll
        for (int reg = 0; reg < 4; ++reg) {
            const float inv = 1.f / sums[w][mi * 16 + lg * 4 + reg];
            const int tok = qb * 64 + w * 32 + mi * 16 + lg * 4 + reg;
            const size_t base = ((size_t)(b_ * 1024 + tok)) * 768 + h * 64;
#pragma unroll
            for (int fj = 0; fj < 4; ++fj)
                AO[base + fj * 16 + l15] = (_Float16)(o[mi][fj][reg] * inv);
        }
}

// ---------------- launcher ----------------
extern "C" void kernel_launch(void* const* d_in, const int* in_sizes, int n_in,
                              void* d_out, int out_size, void* d_ws, size_t ws_size,
                              hipStream_t stream) {
    (void)in_sizes; (void)n_in; (void)out_size; (void)ws_size;
    const float* x      = (const float*)d_in[0];
    const float* qkv_w  = (const float*)d_in[1];
    const float* qkv_b  = (const float*)d_in[2];
    const float* q_bw   = (const float*)d_in[3];
    const float* q_bb   = (const float*)d_in[4];
    const float* q_A    = (const float*)d_in[5];
    const float* q_B    = (const float*)d_in[6];
    const float* k_bw   = (const float*)d_in[7];
    const float* k_bb   = (const float*)d_in[8];
    const float* k_A    = (const float*)d_in[9];
    const float* k_B    = (const float*)d_in[10];
    const float* proj_w = (const float*)d_in[11];
    const float* proj_b = (const float*)d_in[12];
    float* out = (float*)d_out;
    char*  ws  = (char*)d_ws;

    _Float16* Wx = (_Float16*)(ws + OFF_WX);
    _Float16* Ph = (_Float16*)(ws + OFF_PH);
    _Float16* Xe = (_Float16*)(ws + OFF_XE);
    _Float16* Qh = (_Float16*)(ws + OFF_QH);
    _Float16* Kh = (_Float16*)(ws + OFF_KH);
    _Float16* Vt = (_Float16*)(ws + OFF_VT);
    _Float16* AO = (_Float16*)(ws + OFF_AO);

    pre<<<dim3(3392), dim3(256), 0, stream>>>(qkv_w, qkv_b, q_bw, q_bb, k_bw, k_bb,
                                              proj_w, q_B, k_B, x, q_A, k_A, Wx, Ph, Xe);
    gemm_h<128, 96, 0><<<dim3(24, 32), dim3(256), 0, stream>>>(
        Xe, Wx, 800, 800, 25, nullptr, Qh, Kh, Vt, nullptr);
    attn5<<<dim3(16, 48), dim3(128), 0, stream>>>(Qh, Kh, Vt, AO);
    gemm_h<64, 96, 1><<<dim3(8, 64), dim3(256), 0, stream>>>(
        AO, Ph, 768, 768, 24, proj_b, nullptr, nullptr, nullptr, out);
}